// Round 1
// baseline (267.985 us; speedup 1.0000x reference)
//
#include <hip/hip_runtime.h>
#include <stdint.h>

// ---------------- types ----------------
typedef short shortx8 __attribute__((ext_vector_type(8)));
typedef float floatx4 __attribute__((ext_vector_type(4)));

#define T_LEN 2048
#define BATCH 16
#define DMODEL 512
#define HDIM 512
#define M_ROWS (T_LEN * BATCH)          // 32768
#define NCHUNK 32
#define LCHUNK 64                        // T per chunk
#define NCHAIN (BATCH * HDIM)            // 8192
#define Y_ELEMS (M_ROWS * DMODEL)        // 16777216

// ---------------- helpers ----------------
__device__ __forceinline__ unsigned short f2bf(float f) {
    union { float f; unsigned u; } v; v.f = f;
    unsigned r = (v.u + 0x7FFFu + ((v.u >> 16) & 1u)) >> 16;
    return (unsigned short)r;
}
__device__ __forceinline__ float bf2f(unsigned short u) {
    union { unsigned u; float f; } v; v.u = ((unsigned)u) << 16;
    return v.f;
}

// ---------------- prep: per-channel Lam, Lam^64, gamma ----------------
__global__ void prep_kernel(const float* __restrict__ nu_log, const float* __restrict__ th_log,
                            float* lam_re, float* lam_im, float* l64_re, float* l64_im, float* gam) {
    int h = blockIdx.x * blockDim.x + threadIdx.x;
    if (h >= HDIM) return;
    double nu  = exp((double)nu_log[h]);
    double th  = exp((double)th_log[h]);
    double mag = exp(-nu);
    double lre = mag * cos(th), lim = mag * sin(th);
    double g   = sqrt(1.0 - exp(-2.0 * nu));
    double zr = lre, zi = lim;
    for (int i = 0; i < 6; ++i) { double nr = zr*zr - zi*zi; zi = 2.0*zr*zi; zr = nr; }
    lam_re[h] = (float)lre; lam_im[h] = (float)lim;
    l64_re[h] = (float)zr;  l64_im[h] = (float)zi;
    gam[h] = (float)g;
}

// ---------------- merged operand conversion ----------------
__global__ void conv_BC_kernel(const float* __restrict__ B_re, const float* __restrict__ B_im,
                               const float* __restrict__ gam,
                               const float* __restrict__ C_re, const float* __restrict__ C_im,
                               unsigned short* __restrict__ Bs, unsigned short* __restrict__ C2) {
    int idx = blockIdx.x * blockDim.x + threadIdx.x;     // 0 .. 1M-1
    if (idx < 524288) {
        int n = idx >> 9;        // /512
        int d = idx & 511;
        int h = n & 511;
        float v = (n < HDIM ? B_re[h * DMODEL + d] : B_im[h * DMODEL + d]) * gam[h];
        Bs[idx] = f2bf(v);
    } else {
        int i2 = idx - 524288;
        int d = i2 >> 10;        // /1024
        int k = i2 & 1023;
        float v = (k < HDIM) ? C_re[d * HDIM + k] : -C_im[d * HDIM + (k - HDIM)];
        C2[i2] = f2bf(v);
    }
}

// ---------------- cast x fp32 -> bf16 ----------------
__global__ void cast_x_kernel(const float4* __restrict__ x4, unsigned short* __restrict__ xb, int n4) {
    int i = blockIdx.x * blockDim.x + threadIdx.x;
    if (i >= n4) return;
    float4 v = x4[i];
    ushort4 u;
    u.x = f2bf(v.x); u.y = f2bf(v.y); u.z = f2bf(v.z); u.w = f2bf(v.w);
    *(ushort4*)(xb + (size_t)i * 4) = u;
}

// ======================================================================
// 8-phase 256x256 NT GEMM (T2+T3+T4+T5 port, plain HIP).
// A: M x K row-major bf16.  Bm: N x K row-major bf16.  D[m][n] = sum_k A[m][k]*Bm[n][k]
//
// Geometry: 512 thr = 8 waves (2M x 4N). Wave output 128x64, HALF-INTERLEAVED:
//   out rows = bm*256 + mh*128 + wr*64 + mi*16 + qq*4 + r   (mh in {0,1})
//   out cols = bn*256 + nh*128 + wc*32 + ni*16 + lrow       (nh in {0,1})
// so phase-quadrant (mh,nh) reads exactly one contiguous 128-row LDS half of
// A and of B -> staged half-tiles overwrite halves freed >=2 phases earlier.
//
// LDS 128 KiB: As/Bs[2 buf][2 half][128*64] bf16. 16B-chunk swizzle c ^= r&7
// on both the pre-swizzled GLOBAL source (global_load_lds dest stays linear,
// m104/m173 rule) and the ds_read side -> 0 bank conflicts (carried over).
//
// Schedule (phases p1..p8 per iter; buf0=K-tile 2i, buf1=2i+1):
//   p1: Q(0,0)b0, ld A0+B0 | stage buf1.B1<-k(2i+1)   p5: Q(0,0)b1 | buf0.B1<-k+2
//   p2: Q(0,1)b0, ld B1    | stage buf1.A1<-k(2i+1)   p6: Q(0,1)b1 | buf0.A1<-k+2
//   p3: Q(1,0)b0, ld A1    | stage buf0.A0<-k+2       p7: Q(1,0)b1 | buf1.A0<-k+3
//   p4: Q(1,1)b0           | stage buf0.B0<-k+2       p8: Q(1,1)b1 | buf1.B0<-k+3
// Stage->read distance is 5-6 phases everywhere; s_waitcnt vmcnt(6) at END of
// every phase (2 loads/phase -> issues <= p-3 complete) guarantees reads at
// p+4. WAR is protected by barrier2: every staged half was last ds_read >=2
// phases before its stage issue. vmcnt never drains to 0 in the loop (T4).
// ======================================================================

#define STAGE_GEN(arr, src, rbase, buf, half, kt) do { \
    _Pragma("unroll") \
    for (int j_ = 0; j_ < 2; ++j_) { \
        int ch_ = j_ * 512 + tid; \
        int r_ = ch_ >> 3, c_ = ch_ & 7; \
        int g_ = c_ ^ (r_ & 7); \
        const unsigned short* gp_ = src + ((rbase) + (size_t)((half) * 128 + r_)) * K + ((kt) * 64 + g_ * 8); \
        unsigned short* lp_ = &arr[buf][half][0] + ch_ * 8; \
        __builtin_amdgcn_global_load_lds((const __attribute__((address_space(1))) void*)gp_, \
            (__attribute__((address_space(3))) void*)lp_, 16, 0, 0); \
    } } while (0)
#define STAGE_A(buf, half, kt) STAGE_GEN(As, A,  rowA, buf, half, kt)
#define STAGE_B(buf, half, kt) STAGE_GEN(Bs, Bm, rowB, buf, half, kt)

#define LDA8(dst, buf, mh) do { \
    _Pragma("unroll") \
    for (int mi_ = 0; mi_ < 4; ++mi_) { \
        int r_ = wr * 64 + mi_ * 16 + lrow; \
        _Pragma("unroll") \
        for (int s_ = 0; s_ < 2; ++s_) { \
            int c_ = (s_ * 4 + qq) ^ (r_ & 7); \
            dst[mi_][s_] = *(const shortx8*)&As[buf][mh][r_ * 64 + c_ * 8]; \
        } } } while (0)

#define LDB4(dst, buf, nh) do { \
    _Pragma("unroll") \
    for (int ni_ = 0; ni_ < 2; ++ni_) { \
        int r_ = wc * 32 + ni_ * 16 + lrow; \
        _Pragma("unroll") \
        for (int s_ = 0; s_ < 2; ++s_) { \
            int c_ = (s_ * 4 + qq) ^ (r_ & 7); \
            dst[ni_][s_] = *(const shortx8*)&Bs[buf][nh][r_ * 64 + c_ * 8]; \
        } } } while (0)

#define MFMA_Q(mh, nh, AF, BF) do { \
    _Pragma("unroll") \
    for (int s_ = 0; s_ < 2; ++s_) \
    _Pragma("unroll") \
    for (int mi_ = 0; mi_ < 4; ++mi_) \
    _Pragma("unroll") \
    for (int ni_ = 0; ni_ < 2; ++ni_) \
        acc[mh][mi_][nh][ni_] = __builtin_amdgcn_mfma_f32_16x16x32_bf16(AF[mi_][s_], BF[ni_][s_], acc[mh][mi_][nh][ni_], 0, 0, 0); \
    } while (0)

#define PHASE_MID do { \
    __builtin_amdgcn_s_barrier(); \
    asm volatile("s_waitcnt lgkmcnt(0)" ::: "memory"); \
    __builtin_amdgcn_s_setprio(1); } while (0)

#define PHASE_END do { \
    __builtin_amdgcn_s_setprio(0); \
    asm volatile("s_waitcnt vmcnt(6)" ::: "memory"); \
    __builtin_amdgcn_s_barrier(); } while (0)

// MODE 0: OutB[m*N+n] = bf16(acc)
// MODE 1: OutF[m*N+n] = acc + Dv[n]*bf2f(Xb[m*N+n])
template <int MODE>
__global__ __launch_bounds__(512, 2) void gemm_nt2(const unsigned short* __restrict__ A,
                                                   const unsigned short* __restrict__ Bm,
                                                   const int K, const int N, const int lgNB,
                                                   const int mstride,
                                                   unsigned short* __restrict__ OutB,
                                                   float* __restrict__ OutF,
                                                   const float* __restrict__ Dv,
                                                   const unsigned short* __restrict__ Xb) {
    __shared__ __align__(16) unsigned short As[2][2][128 * 64];
    __shared__ __align__(16) unsigned short Bs[2][2][128 * 64];
    const int L = blockIdx.x;
    const int xcd = L & 7, slot = L >> 3;
    const int bn = slot & ((1 << lgNB) - 1);
    const int bm = xcd * mstride + (slot >> lgNB);
    const int tid = threadIdx.x;
    const int lane = tid & 63, wv = tid >> 6;
    const int wr = wv >> 2, wc = wv & 3;
    const int lrow = lane & 15, qq = lane >> 4;
    const int NKT = K >> 6, NITER = K >> 7;
    const size_t rowA = (size_t)bm * 256, rowB = (size_t)bn * 256;

    floatx4 acc[2][4][2][2] = {};
    shortx8 af[4][2], bf0[2][2], bf1[2][2];

    // prologue: K0 all 4 halves -> buf0; K1 A0,B0 -> buf1 (issue order matters:
    // vmcnt(8) leaves exactly the last 4 loads outstanding -> buf0.A0/B0 landed)
    STAGE_A(0, 0, 0); STAGE_B(0, 0, 0); STAGE_B(0, 1, 0); STAGE_A(0, 1, 0);
    STAGE_A(1, 0, 1); STAGE_B(1, 0, 1);
    asm volatile("s_waitcnt vmcnt(8)" ::: "memory");
    __builtin_amdgcn_s_barrier();

    for (int i = 0; i < NITER; ++i) {
        int k1 = 2 * i + 1;
        int k2 = 2 * i + 2; if (k2 > NKT - 1) k2 = NKT - 1;   // clamp (never skip:
        int k3 = 2 * i + 3; if (k3 > NKT - 1) k3 = NKT - 1;   // vmcnt counts must stay uniform)

        // p1: Q(0,0) buf0
        LDA8(af, 0, 0); LDB4(bf0, 0, 0);
        STAGE_B(1, 1, k1);
        PHASE_MID; MFMA_Q(0, 0, af, bf0); PHASE_END;
        // p2: Q(0,1)
        LDB4(bf1, 0, 1);
        STAGE_A(1, 1, k1);
        PHASE_MID; MFMA_Q(0, 1, af, bf1); PHASE_END;
        // p3: Q(1,0)
        LDA8(af, 0, 1);
        STAGE_A(0, 0, k2);
        PHASE_MID; MFMA_Q(1, 0, af, bf0); PHASE_END;
        // p4: Q(1,1)
        STAGE_B(0, 0, k2);
        PHASE_MID; MFMA_Q(1, 1, af, bf1); PHASE_END;
        // p5: Q(0,0) buf1
        LDA8(af, 1, 0); LDB4(bf0, 1, 0);
        STAGE_B(0, 1, k2);
        PHASE_MID; MFMA_Q(0, 0, af, bf0); PHASE_END;
        // p6: Q(0,1)
        LDB4(bf1, 1, 1);
        STAGE_A(0, 1, k2);
        PHASE_MID; MFMA_Q(0, 1, af, bf1); PHASE_END;
        // p7: Q(1,0)
        LDA8(af, 1, 1);
        STAGE_A(1, 0, k3);
        PHASE_MID; MFMA_Q(1, 0, af, bf0); PHASE_END;
        // p8: Q(1,1)
        STAGE_B(1, 0, k3);
        PHASE_MID; MFMA_Q(1, 1, af, bf1); PHASE_END;
    }
    // drain in-flight LDS-DMA before wave exit (clamped dummy stages)
    asm volatile("s_waitcnt vmcnt(0)" ::: "memory");

    // epilogue: D row = qq*4 + r, col = lrow (m89/m91-verified C/D mapping)
    #pragma unroll
    for (int mh = 0; mh < 2; ++mh)
    #pragma unroll
    for (int mi = 0; mi < 4; ++mi) {
        int mbase = bm * 256 + mh * 128 + wr * 64 + mi * 16 + qq * 4;
        #pragma unroll
        for (int nh = 0; nh < 2; ++nh)
        #pragma unroll
        for (int ni = 0; ni < 2; ++ni) {
            int n = bn * 256 + nh * 128 + wc * 32 + ni * 16 + lrow;
            if (MODE == 0) {
                #pragma unroll
                for (int r = 0; r < 4; ++r)
                    OutB[(size_t)(mbase + r) * N + n] = f2bf(acc[mh][mi][nh][ni][r]);
            } else {
                float dv = Dv[n];
                #pragma unroll
                for (int r = 0; r < 4; ++r) {
                    size_t idx = (size_t)(mbase + r) * N + n;
                    OutF[idx] = acc[mh][mi][nh][ni][r] + dv * bf2f(Xb[idx]);
                }
            }
        }
    }
}

// ---------------- scan pass 1: per-chunk partial (zero init), 2 channels/thread -----
__global__ void scan_partial(const unsigned short* __restrict__ Bu,
                             const float* __restrict__ lam_re, const float* __restrict__ lam_im,
                             float* __restrict__ car_re, float* __restrict__ car_im) {
    int gid = blockIdx.x * blockDim.x + threadIdx.x;     // 0 .. 32*4096-1
    int chunk = gid >> 12;
    int idx = gid & 4095;
    int b = idx >> 8, hp = idx & 255;
    int h = hp * 2;
    float lr0 = lam_re[h], li0 = lam_im[h];
    float lr1 = lam_re[h + 1], li1 = lam_im[h + 1];
    float v0r = 0.f, v0i = 0.f, v1r = 0.f, v1i = 0.f;
    const unsigned short* p = Bu + (size_t)chunk * LCHUNK * BATCH * 1024 + (size_t)b * 1024 + h;
    for (int j = 0; j < LCHUNK; ++j) {
        unsigned rr = *(const unsigned*)p;
        unsigned ii = *(const unsigned*)(p + 512);
        float b0r = bf2f((unsigned short)rr), b1r = bf2f((unsigned short)(rr >> 16));
        float b0i = bf2f((unsigned short)ii), b1i = bf2f((unsigned short)(ii >> 16));
        float n0r = lr0 * v0r - li0 * v0i + b0r;
        float n0i = lr0 * v0i + li0 * v0r + b0i;
        float n1r = lr1 * v1r - li1 * v1i + b1r;
        float n1i = lr1 * v1i + li1 * v1r + b1i;
        v0r = n0r; v0i = n0i; v1r = n1r; v1i = n1i;
        p += BATCH * 1024;
    }
    int c = b * 512 + h;
    *(float2*)&car_re[chunk * NCHAIN + c] = make_float2(v0r, v1r);
    *(float2*)&car_im[chunk * NCHAIN + c] = make_float2(v0i, v1i);
}

// ---------------- scan pass 2 (fused combine+apply) ----------------
__global__ void scan_apply(unsigned short* __restrict__ Bu,
                           const float* __restrict__ lam_re, const float* __restrict__ lam_im,
                           const float* __restrict__ l64_re, const float* __restrict__ l64_im,
                           const float* __restrict__ h0_re, const float* __restrict__ h0_im,
                           const float* __restrict__ car_re, const float* __restrict__ car_im,
                           float* __restrict__ out_final, int interleave) {
    int gid = blockIdx.x * blockDim.x + threadIdx.x;
    int chunk = gid >> 12;           // block-uniform
    int idx = gid & 4095;
    int b = idx >> 8, hp = idx & 255;
    int h = hp * 2;
    int c = b * 512 + h;
    float L0r = l64_re[h], L0i = l64_im[h];
    float L1r = l64_re[h + 1], L1i = l64_im[h + 1];
    float v0r = h0_re[c], v0i = h0_im[c];
    float v1r = h0_re[c + 1], v1i = h0_im[c + 1];
    for (int k = 0; k < chunk; ++k) {
        float2 crr = *(const float2*)&car_re[k * NCHAIN + c];
        float2 cii = *(const float2*)&car_im[k * NCHAIN + c];
        float n0r = L0r * v0r - L0i * v0i + crr.x;
        float n0i = L0r * v0i + L0i * v0r + cii.x;
        float n1r = L1r * v1r - L1i * v1i + crr.y;
        float n1i = L1r * v1i + L1i * v1r + cii.y;
        v0r = n0r; v0i = n0i; v1r = n1r; v1i = n1i;
    }
    float lr0 = lam_re[h], li0 = lam_im[h];
    float lr1 = lam_re[h + 1], li1 = lam_im[h + 1];
    unsigned short* p = Bu + (size_t)chunk * LCHUNK * BATCH * 1024 + (size_t)b * 1024 + h;
    for (int j = 0; j < LCHUNK; ++j) {
        unsigned rr = *(const unsigned*)p;
        unsigned ii = *(const unsigned*)(p + 512);
        float b0r = bf2f((unsigned short)rr), b1r = bf2f((unsigned short)(rr >> 16));
        float b0i = bf2f((unsigned short)ii), b1i = bf2f((unsigned short)(ii >> 16));
        float n0r = lr0 * v0r - li0 * v0i + b0r;
        float n0i = lr0 * v0i + li0 * v0r + b0i;
        float n1r = lr1 * v1r - li1 * v1i + b1r;
        float n1i = lr1 * v1i + li1 * v1r + b1i;
        v0r = n0r; v0i = n0i; v1r = n1r; v1i = n1i;
        *(unsigned*)p         = (unsigned)f2bf(v0r) | ((unsigned)f2bf(v1r) << 16);
        *(unsigned*)(p + 512) = (unsigned)f2bf(v0i) | ((unsigned)f2bf(v1i) << 16);
        p += BATCH * 1024;
    }
    if (chunk == NCHUNK - 1) {       // final_state = h[T-1]
        if (interleave) {
            out_final[2 * c]     = v0r;
            out_final[2 * c + 1] = v0i;
            out_final[2 * c + 2] = v1r;
            out_final[2 * c + 3] = v1i;
        } else {
            out_final[c]     = v0r;
            out_final[c + 1] = v1r;
        }
    }
}

// ---------------- launch ----------------
extern "C" void kernel_launch(void* const* d_in, const int* in_sizes, int n_in,
                              void* d_out, int out_size, void* d_ws, size_t ws_size,
                              hipStream_t stream) {
    const float* x        = (const float*)d_in[0];
    const float* h0_re    = (const float*)d_in[1];
    const float* h0_im    = (const float*)d_in[2];
    const float* nu_log   = (const float*)d_in[3];
    const float* theta_lg = (const float*)d_in[4];
    const float* B_re     = (const float*)d_in[5];
    const float* B_im     = (const float*)d_in[6];
    const float* C_re     = (const float*)d_in[7];
    const float* C_im     = (const float*)d_in[8];
    const float* D_vec    = (const float*)d_in[9];

    // workspace layout (~102 MB total)
    char* ws = (char*)d_ws;
    unsigned short* BuH  = (unsigned short*)(ws + 0);              // 64 MB  (M x 1024 bf16): Bu, then h in-place
    unsigned short* xb   = (unsigned short*)(ws + 67108864);       // 32 MB  (M x 512 bf16)
    unsigned short* Bs   = (unsigned short*)(ws + 100663296);      // 1 MB   (1024 x 512 bf16)
    unsigned short* C2   = (unsigned short*)(ws + 101711872);      // 1 MB   (512 x 1024 bf16)
    float* car_re        = (float*)(ws + 102760448);               // 1 MB
    float* car_im        = (float*)(ws + 103809024);               // 1 MB
    float* lam_re        = (float*)(ws + 104857600);
    float* lam_im        = (float*)(ws + 104859648);
    float* l64_re        = (float*)(ws + 104861696);
    float* l64_im        = (float*)(ws + 104863744);
    float* gam           = (float*)(ws + 104865792);

    // adaptive d_out layout: out_size = Y_ELEMS + {16384 interleaved | 8192 real-only}
    int fs_elems = out_size - Y_ELEMS;
    int interleave = (fs_elems == 8192) ? 0 : 1;
    if (fs_elems != 8192) fs_elems = 16384;
    float* out_final = (float*)d_out;
    float* y_out     = (float*)d_out + fs_elems;

    // 1. channel constants
    prep_kernel<<<2, 256, 0, stream>>>(nu_log, theta_lg, lam_re, lam_im, l64_re, l64_im, gam);
    // 2. operand conversions (merged) + x cast
    conv_BC_kernel<<<(1048576) / 256, 256, 0, stream>>>(B_re, B_im, gam, C_re, C_im, Bs, C2);
    cast_x_kernel<<<(Y_ELEMS / 4) / 256, 256, 0, stream>>>((const float4*)x, xb, Y_ELEMS / 4);
    // 3. GEMM1: Bu = xb (32768 x 512) . Bs^T (1024 x 512) -> M x 1024 bf16
    //    grid = 8 xcd * 16 mslots * 4 nslots = 512 blocks of 512 thr
    gemm_nt2<0><<<512, 512, 0, stream>>>(xb, Bs, DMODEL, 1024, 2, 16, BuH, nullptr, nullptr, nullptr);
    // 4. chunked scan over T (partial -> fused prefix+apply, h overwrites Bu in-place)
    scan_partial<<<(NCHUNK * NCHAIN / 2) / 256, 256, 0, stream>>>(BuH, lam_re, lam_im, car_re, car_im);
    scan_apply<<<(NCHUNK * NCHAIN / 2) / 256, 256, 0, stream>>>(BuH, lam_re, lam_im, l64_re, l64_im,
                                                                h0_re, h0_im, car_re, car_im,
                                                                out_final, interleave);
    // 5. GEMM2: y = h (32768 x 1024) . C2^T (512 x 1024) + Dv*xb -> M x 512 fp32
    //    grid = 8 xcd * 16 mslots * 2 nslots = 256 blocks of 512 thr
    gemm_nt2<1><<<256, 512, 0, stream>>>(BuH, C2, 1024, 512, 1, 16, nullptr, y_out, D_vec, xb);
}

// Round 2
// 263.407 us; speedup vs baseline: 1.0174x; 1.0174x over previous
//
#include <hip/hip_runtime.h>
#include <stdint.h>

// ---------------- types ----------------
typedef short shortx8 __attribute__((ext_vector_type(8)));
typedef float floatx4 __attribute__((ext_vector_type(4)));

#define T_LEN 2048
#define BATCH 16
#define DMODEL 512
#define HDIM 512
#define M_ROWS (T_LEN * BATCH)          // 32768
#define NCHUNK 32
#define LCHUNK 64                        // T per chunk
#define NCHAIN (BATCH * HDIM)            // 8192
#define Y_ELEMS (M_ROWS * DMODEL)        // 16777216

// ---------------- helpers ----------------
__device__ __forceinline__ unsigned short f2bf(float f) {
    union { float f; unsigned u; } v; v.f = f;
    unsigned r = (v.u + 0x7FFFu + ((v.u >> 16) & 1u)) >> 16;
    return (unsigned short)r;
}
__device__ __forceinline__ float bf2f(unsigned short u) {
    union { unsigned u; float f; } v; v.u = ((unsigned)u) << 16;
    return v.f;
}

// ---------------- prep: per-channel Lam, Lam^64, gamma ----------------
__global__ void prep_kernel(const float* __restrict__ nu_log, const float* __restrict__ th_log,
                            float* lam_re, float* lam_im, float* l64_re, float* l64_im, float* gam) {
    int h = blockIdx.x * blockDim.x + threadIdx.x;
    if (h >= HDIM) return;
    double nu  = exp((double)nu_log[h]);
    double th  = exp((double)th_log[h]);
    double mag = exp(-nu);
    double lre = mag * cos(th), lim = mag * sin(th);
    double g   = sqrt(1.0 - exp(-2.0 * nu));
    double zr = lre, zi = lim;
    for (int i = 0; i < 6; ++i) { double nr = zr*zr - zi*zi; zi = 2.0*zr*zi; zr = nr; }
    lam_re[h] = (float)lre; lam_im[h] = (float)lim;
    l64_re[h] = (float)zr;  l64_im[h] = (float)zi;
    gam[h] = (float)g;
}

// ---------------- merged operand conversion ----------------
__global__ void conv_BC_kernel(const float* __restrict__ B_re, const float* __restrict__ B_im,
                               const float* __restrict__ gam,
                               const float* __restrict__ C_re, const float* __restrict__ C_im,
                               unsigned short* __restrict__ Bs, unsigned short* __restrict__ C2) {
    int idx = blockIdx.x * blockDim.x + threadIdx.x;     // 0 .. 1M-1
    if (idx < 524288) {
        int n = idx >> 9;        // /512
        int d = idx & 511;
        int h = n & 511;
        float v = (n < HDIM ? B_re[h * DMODEL + d] : B_im[h * DMODEL + d]) * gam[h];
        Bs[idx] = f2bf(v);
    } else {
        int i2 = idx - 524288;
        int d = i2 >> 10;        // /1024
        int k = i2 & 1023;
        float v = (k < HDIM) ? C_re[d * HDIM + k] : -C_im[d * HDIM + (k - HDIM)];
        C2[i2] = f2bf(v);
    }
}

// ---------------- cast x fp32 -> bf16 ----------------
__global__ void cast_x_kernel(const float4* __restrict__ x4, unsigned short* __restrict__ xb, int n4) {
    int i = blockIdx.x * blockDim.x + threadIdx.x;
    if (i >= n4) return;
    float4 v = x4[i];
    ushort4 u;
    u.x = f2bf(v.x); u.y = f2bf(v.y); u.z = f2bf(v.z); u.w = f2bf(v.w);
    *(ushort4*)(xb + (size_t)i * 4) = u;
}

// ======================================================================
// 8-phase 256x256 NT GEMM — m201 template with waits ONLY at p4/p8 (T4).
// A: M x K row-major bf16.  Bm: N x K row-major bf16.  D[m][n] = sum_k A[m][k]*Bm[n][k]
//
// Round-1 post-mortem: per-phase vmcnt(6) (16 gates/iter) exposed load
// latency to all 8 waves at every phase (1 block/CU -> no inter-block
// cover) -> 690 TF, MfmaUtil 25%.  This version: stage map reordered so
// every stage->read distance >= 6 phases; exactly TWO vmcnt(6) waits per
// iteration (p4, p8), matching m218's counted-wait lever.
//
// Stage map (iter i; k1=2i+1, k2=2i+2, k3=2i+3; buf0=tile 2i, buf1=2i+1):
//   p1: b1.A1<-k1   p2: b0.A0<-k2   p3: b0.B0<-k2   p4: b0.B1<-k2 [vmcnt(6)]
//   p5: b0.A1<-k2   p6: b1.A0<-k3   p7: b1.B0<-k3   p8: b1.B1<-k3 [vmcnt(6)]
// Reads (quadrants): p1 A0+B0/b0, p2 B1/b0, p3 A1/b0, p4 -, p5..p8 same on b1.
// Coverage (2 loads/stage; vmcnt(6) => all but last 3 stages complete):
//   wait@p4 covers through p1's stage  -> p5 (b1.A0,B0 = prev p6,p7),
//     p6 (b1.B1 = prev p8), p7 (b1.A1 = p1)  all OK
//   wait@p8 covers through p5's stage  -> next p1 (b0.A0,B0 = p2,p3),
//     p2 (b0.B1 = p4), p3 (b0.A1 = p5)  all OK (exactly covered)
// WAR: each staged half was last ds_read >=1 phase (2 barriers) before its
// stage issue; reads complete at the consumer's lgkmcnt(0).  vmcnt never
// drains to 0 in the loop.
// ======================================================================

#define STAGE_GEN(arr, src, rbase, buf, half, kt) do { \
    _Pragma("unroll") \
    for (int j_ = 0; j_ < 2; ++j_) { \
        int ch_ = j_ * 512 + tid; \
        int r_ = ch_ >> 3, c_ = ch_ & 7; \
        int g_ = c_ ^ (r_ & 7); \
        const unsigned short* gp_ = src + ((rbase) + (size_t)((half) * 128 + r_)) * K + ((kt) * 64 + g_ * 8); \
        unsigned short* lp_ = &arr[buf][half][0] + ch_ * 8; \
        __builtin_amdgcn_global_load_lds((const __attribute__((address_space(1))) void*)gp_, \
            (__attribute__((address_space(3))) void*)lp_, 16, 0, 0); \
    } } while (0)
#define STAGE_A(buf, half, kt) STAGE_GEN(As, A,  rowA, buf, half, kt)
#define STAGE_B(buf, half, kt) STAGE_GEN(Bs, Bm, rowB, buf, half, kt)

#define LDA8(dst, buf, mh) do { \
    _Pragma("unroll") \
    for (int mi_ = 0; mi_ < 4; ++mi_) { \
        int r_ = wr * 64 + mi_ * 16 + lrow; \
        _Pragma("unroll") \
        for (int s_ = 0; s_ < 2; ++s_) { \
            int c_ = (s_ * 4 + qq) ^ (r_ & 7); \
            dst[mi_][s_] = *(const shortx8*)&As[buf][mh][r_ * 64 + c_ * 8]; \
        } } } while (0)

#define LDB4(dst, buf, nh) do { \
    _Pragma("unroll") \
    for (int ni_ = 0; ni_ < 2; ++ni_) { \
        int r_ = wc * 32 + ni_ * 16 + lrow; \
        _Pragma("unroll") \
        for (int s_ = 0; s_ < 2; ++s_) { \
            int c_ = (s_ * 4 + qq) ^ (r_ & 7); \
            dst[ni_][s_] = *(const shortx8*)&Bs[buf][nh][r_ * 64 + c_ * 8]; \
        } } } while (0)

#define MFMA_Q(mh, nh, AF, BF) do { \
    _Pragma("unroll") \
    for (int s_ = 0; s_ < 2; ++s_) \
    _Pragma("unroll") \
    for (int mi_ = 0; mi_ < 4; ++mi_) \
    _Pragma("unroll") \
    for (int ni_ = 0; ni_ < 2; ++ni_) \
        acc[mh][mi_][nh][ni_] = __builtin_amdgcn_mfma_f32_16x16x32_bf16(AF[mi_][s_], BF[ni_][s_], acc[mh][mi_][nh][ni_], 0, 0, 0); \
    } while (0)

#define PHASE_MID do { \
    __builtin_amdgcn_s_barrier(); \
    asm volatile("s_waitcnt lgkmcnt(0)" ::: "memory"); \
    __builtin_amdgcn_s_setprio(1); } while (0)

// no vmem wait in the common phase end (T4: never drain in-loop)
#define PHASE_END do { \
    __builtin_amdgcn_s_setprio(0); \
    __builtin_amdgcn_s_barrier(); } while (0)

// counted wait, only at p4 and p8
#define PHASE_END_W do { \
    __builtin_amdgcn_s_setprio(0); \
    asm volatile("s_waitcnt vmcnt(6)" ::: "memory"); \
    __builtin_amdgcn_s_barrier(); } while (0)

// MODE 0: OutB[m*N+n] = bf16(acc)
// MODE 1: OutF[m*N+n] = acc + Dv[n]*bf2f(Xb[m*N+n])
template <int MODE>
__global__ __launch_bounds__(512, 2) void gemm_nt2(const unsigned short* __restrict__ A,
                                                   const unsigned short* __restrict__ Bm,
                                                   const int K, const int N, const int lgNB,
                                                   const int mstride,
                                                   unsigned short* __restrict__ OutB,
                                                   float* __restrict__ OutF,
                                                   const float* __restrict__ Dv,
                                                   const unsigned short* __restrict__ Xb) {
    __shared__ __align__(16) unsigned short As[2][2][128 * 64];
    __shared__ __align__(16) unsigned short Bs[2][2][128 * 64];
    const int L = blockIdx.x;
    const int xcd = L & 7, slot = L >> 3;
    const int bn = slot & ((1 << lgNB) - 1);
    const int bm = xcd * mstride + (slot >> lgNB);
    const int tid = threadIdx.x;
    const int lane = tid & 63, wv = tid >> 6;
    const int wr = wv >> 2, wc = wv & 3;
    const int lrow = lane & 15, qq = lane >> 4;
    const int NKT = K >> 6, NITER = K >> 7;
    const size_t rowA = (size_t)bm * 256, rowB = (size_t)bn * 256;

    floatx4 acc[2][4][2][2] = {};
    shortx8 af[4][2], bf0[2][2], bf1[2][2];

    // prologue: 7 half-tiles, ISSUE ORDER = [b0.A0 b0.B0 b0.B1 b0.A1 | b1.A0 b1.B0 b1.B1]
    // (14 loads). vmcnt(6) -> loads 1..8 complete = all of buf0 (covers p1..p3 reads).
    // b1.A0/B0/B1 (loads 9..14) are covered by iter0-p4's vmcnt(6) (through p1's stage).
    STAGE_A(0, 0, 0); STAGE_B(0, 0, 0); STAGE_B(0, 1, 0); STAGE_A(0, 1, 0);
    STAGE_A(1, 0, 1); STAGE_B(1, 0, 1); STAGE_B(1, 1, 1);
    asm volatile("s_waitcnt vmcnt(6)" ::: "memory");
    __builtin_amdgcn_s_barrier();

    for (int i = 0; i < NITER; ++i) {
        int k1 = 2 * i + 1;
        int k2 = 2 * i + 2; if (k2 > NKT - 1) k2 = NKT - 1;   // clamp (never skip:
        int k3 = 2 * i + 3; if (k3 > NKT - 1) k3 = NKT - 1;   // vmcnt counts stay uniform)

        // p1: Q(0,0) buf0
        LDA8(af, 0, 0); LDB4(bf0, 0, 0);
        STAGE_A(1, 1, k1);
        PHASE_MID; MFMA_Q(0, 0, af, bf0); PHASE_END;
        // p2: Q(0,1) buf0
        LDB4(bf1, 0, 1);
        STAGE_A(0, 0, k2);
        PHASE_MID; MFMA_Q(0, 1, af, bf1); PHASE_END;
        // p3: Q(1,0) buf0
        LDA8(af, 0, 1);
        STAGE_B(0, 0, k2);
        PHASE_MID; MFMA_Q(1, 0, af, bf0); PHASE_END;
        // p4: Q(1,1) buf0  [counted wait]
        STAGE_B(0, 1, k2);
        PHASE_MID; MFMA_Q(1, 1, af, bf1); PHASE_END_W;
        // p5: Q(0,0) buf1
        LDA8(af, 1, 0); LDB4(bf0, 1, 0);
        STAGE_A(0, 1, k2);
        PHASE_MID; MFMA_Q(0, 0, af, bf0); PHASE_END;
        // p6: Q(0,1) buf1
        LDB4(bf1, 1, 1);
        STAGE_A(1, 0, k3);
        PHASE_MID; MFMA_Q(0, 1, af, bf1); PHASE_END;
        // p7: Q(1,0) buf1
        LDA8(af, 1, 1);
        STAGE_B(1, 0, k3);
        PHASE_MID; MFMA_Q(1, 0, af, bf0); PHASE_END;
        // p8: Q(1,1) buf1  [counted wait]
        STAGE_B(1, 1, k3);
        PHASE_MID; MFMA_Q(1, 1, af, bf1); PHASE_END_W;
    }
    // drain in-flight LDS-DMA before epilogue/exit
    asm volatile("s_waitcnt vmcnt(0)" ::: "memory");

    // epilogue: D row = qq*4 + r, col = lrow (m89/m91-verified C/D mapping)
    #pragma unroll
    for (int mh = 0; mh < 2; ++mh)
    #pragma unroll
    for (int mi = 0; mi < 4; ++mi) {
        int mbase = bm * 256 + mh * 128 + wr * 64 + mi * 16 + qq * 4;
        #pragma unroll
        for (int nh = 0; nh < 2; ++nh)
        #pragma unroll
        for (int ni = 0; ni < 2; ++ni) {
            int n = bn * 256 + nh * 128 + wc * 32 + ni * 16 + lrow;
            if (MODE == 0) {
                #pragma unroll
                for (int r = 0; r < 4; ++r)
                    OutB[(size_t)(mbase + r) * N + n] = f2bf(acc[mh][mi][nh][ni][r]);
            } else {
                float dv = Dv[n];
                #pragma unroll
                for (int r = 0; r < 4; ++r) {
                    size_t idx = (size_t)(mbase + r) * N + n;
                    OutF[idx] = acc[mh][mi][nh][ni][r] + dv * bf2f(Xb[idx]);
                }
            }
        }
    }
}

// ---------------- scan pass 1: per-chunk partial (zero init), 2 channels/thread -----
__global__ void scan_partial(const unsigned short* __restrict__ Bu,
                             const float* __restrict__ lam_re, const float* __restrict__ lam_im,
                             float* __restrict__ car_re, float* __restrict__ car_im) {
    int gid = blockIdx.x * blockDim.x + threadIdx.x;     // 0 .. 32*4096-1
    int chunk = gid >> 12;
    int idx = gid & 4095;
    int b = idx >> 8, hp = idx & 255;
    int h = hp * 2;
    float lr0 = lam_re[h], li0 = lam_im[h];
    float lr1 = lam_re[h + 1], li1 = lam_im[h + 1];
    float v0r = 0.f, v0i = 0.f, v1r = 0.f, v1i = 0.f;
    const unsigned short* p = Bu + (size_t)chunk * LCHUNK * BATCH * 1024 + (size_t)b * 1024 + h;
    for (int j = 0; j < LCHUNK; ++j) {
        unsigned rr = *(const unsigned*)p;
        unsigned ii = *(const unsigned*)(p + 512);
        float b0r = bf2f((unsigned short)rr), b1r = bf2f((unsigned short)(rr >> 16));
        float b0i = bf2f((unsigned short)ii), b1i = bf2f((unsigned short)(ii >> 16));
        float n0r = lr0 * v0r - li0 * v0i + b0r;
        float n0i = lr0 * v0i + li0 * v0r + b0i;
        float n1r = lr1 * v1r - li1 * v1i + b1r;
        float n1i = lr1 * v1i + li1 * v1r + b1i;
        v0r = n0r; v0i = n0i; v1r = n1r; v1i = n1i;
        p += BATCH * 1024;
    }
    int c = b * 512 + h;
    *(float2*)&car_re[chunk * NCHAIN + c] = make_float2(v0r, v1r);
    *(float2*)&car_im[chunk * NCHAIN + c] = make_float2(v0i, v1i);
}

// ---------------- scan pass 2 (fused combine+apply) ----------------
__global__ void scan_apply(unsigned short* __restrict__ Bu,
                           const float* __restrict__ lam_re, const float* __restrict__ lam_im,
                           const float* __restrict__ l64_re, const float* __restrict__ l64_im,
                           const float* __restrict__ h0_re, const float* __restrict__ h0_im,
                           const float* __restrict__ car_re, const float* __restrict__ car_im,
                           float* __restrict__ out_final, int interleave) {
    int gid = blockIdx.x * blockDim.x + threadIdx.x;
    int chunk = gid >> 12;           // block-uniform
    int idx = gid & 4095;
    int b = idx >> 8, hp = idx & 255;
    int h = hp * 2;
    int c = b * 512 + h;
    float L0r = l64_re[h], L0i = l64_im[h];
    float L1r = l64_re[h + 1], L1i = l64_im[h + 1];
    float v0r = h0_re[c], v0i = h0_im[c];
    float v1r = h0_re[c + 1], v1i = h0_im[c + 1];
    for (int k = 0; k < chunk; ++k) {
        float2 crr = *(const float2*)&car_re[k * NCHAIN + c];
        float2 cii = *(const float2*)&car_im[k * NCHAIN + c];
        float n0r = L0r * v0r - L0i * v0i + crr.x;
        float n0i = L0r * v0i + L0i * v0r + cii.x;
        float n1r = L1r * v1r - L1i * v1i + crr.y;
        float n1i = L1r * v1i + L1i * v1r + cii.y;
        v0r = n0r; v0i = n0i; v1r = n1r; v1i = n1i;
    }
    float lr0 = lam_re[h], li0 = lam_im[h];
    float lr1 = lam_re[h + 1], li1 = lam_im[h + 1];
    unsigned short* p = Bu + (size_t)chunk * LCHUNK * BATCH * 1024 + (size_t)b * 1024 + h;
    for (int j = 0; j < LCHUNK; ++j) {
        unsigned rr = *(const unsigned*)p;
        unsigned ii = *(const unsigned*)(p + 512);
        float b0r = bf2f((unsigned short)rr), b1r = bf2f((unsigned short)(rr >> 16));
        float b0i = bf2f((unsigned short)ii), b1i = bf2f((unsigned short)(ii >> 16));
        float n0r = lr0 * v0r - li0 * v0i + b0r;
        float n0i = lr0 * v0i + li0 * v0r + b0i;
        float n1r = lr1 * v1r - li1 * v1i + b1r;
        float n1i = lr1 * v1i + li1 * v1r + b1i;
        v0r = n0r; v0i = n0i; v1r = n1r; v1i = n1i;
        *(unsigned*)p         = (unsigned)f2bf(v0r) | ((unsigned)f2bf(v1r) << 16);
        *(unsigned*)(p + 512) = (unsigned)f2bf(v0i) | ((unsigned)f2bf(v1i) << 16);
        p += BATCH * 1024;
    }
    if (chunk == NCHUNK - 1) {       // final_state = h[T-1]
        if (interleave) {
            out_final[2 * c]     = v0r;
            out_final[2 * c + 1] = v0i;
            out_final[2 * c + 2] = v1r;
            out_final[2 * c + 3] = v1i;
        } else {
            out_final[c]     = v0r;
            out_final[c + 1] = v1r;
        }
    }
}

// ---------------- launch ----------------
extern "C" void kernel_launch(void* const* d_in, const int* in_sizes, int n_in,
                              void* d_out, int out_size, void* d_ws, size_t ws_size,
                              hipStream_t stream) {
    const float* x        = (const float*)d_in[0];
    const float* h0_re    = (const float*)d_in[1];
    const float* h0_im    = (const float*)d_in[2];
    const float* nu_log   = (const float*)d_in[3];
    const float* theta_lg = (const float*)d_in[4];
    const float* B_re     = (const float*)d_in[5];
    const float* B_im     = (const float*)d_in[6];
    const float* C_re     = (const float*)d_in[7];
    const float* C_im     = (const float*)d_in[8];
    const float* D_vec    = (const float*)d_in[9];

    // workspace layout (~102 MB total)
    char* ws = (char*)d_ws;
    unsigned short* BuH  = (unsigned short*)(ws + 0);              // 64 MB  (M x 1024 bf16): Bu, then h in-place
    unsigned short* xb   = (unsigned short*)(ws + 67108864);       // 32 MB  (M x 512 bf16)
    unsigned short* Bs   = (unsigned short*)(ws + 100663296);      // 1 MB   (1024 x 512 bf16)
    unsigned short* C2   = (unsigned short*)(ws + 101711872);      // 1 MB   (512 x 1024 bf16)
    float* car_re        = (float*)(ws + 102760448);               // 1 MB
    float* car_im        = (float*)(ws + 103809024);               // 1 MB
    float* lam_re        = (float*)(ws + 104857600);
    float* lam_im        = (float*)(ws + 104859648);
    float* l64_re        = (float*)(ws + 104861696);
    float* l64_im        = (float*)(ws + 104863744);
    float* gam           = (float*)(ws + 104865792);

    // adaptive d_out layout: out_size = Y_ELEMS + {16384 interleaved | 8192 real-only}
    int fs_elems = out_size - Y_ELEMS;
    int interleave = (fs_elems == 8192) ? 0 : 1;
    if (fs_elems != 8192) fs_elems = 16384;
    float* out_final = (float*)d_out;
    float* y_out     = (float*)d_out + fs_elems;

    // 1. channel constants
    prep_kernel<<<2, 256, 0, stream>>>(nu_log, theta_lg, lam_re, lam_im, l64_re, l64_im, gam);
    // 2. operand conversions (merged) + x cast
    conv_BC_kernel<<<(1048576) / 256, 256, 0, stream>>>(B_re, B_im, gam, C_re, C_im, Bs, C2);
    cast_x_kernel<<<(Y_ELEMS / 4) / 256, 256, 0, stream>>>((const float4*)x, xb, Y_ELEMS / 4);
    // 3. GEMM1: Bu = xb (32768 x 512) . Bs^T (1024 x 512) -> M x 1024 bf16
    //    grid = 8 xcd * 16 mslots * 4 nslots = 512 blocks of 512 thr
    gemm_nt2<0><<<512, 512, 0, stream>>>(xb, Bs, DMODEL, 1024, 2, 16, BuH, nullptr, nullptr, nullptr);
    // 4. chunked scan over T (partial -> fused prefix+apply, h overwrites Bu in-place)
    scan_partial<<<(NCHUNK * NCHAIN / 2) / 256, 256, 0, stream>>>(BuH, lam_re, lam_im, car_re, car_im);
    scan_apply<<<(NCHUNK * NCHAIN / 2) / 256, 256, 0, stream>>>(BuH, lam_re, lam_im, l64_re, l64_im,
                                                                h0_re, h0_im, car_re, car_im,
                                                                out_final, interleave);
    // 5. GEMM2: y = h (32768 x 1024) . C2^T (512 x 1024) + Dv*xb -> M x 512 fp32
    //    grid = 8 xcd * 16 mslots * 2 nslots = 256 blocks of 512 thr
    gemm_nt2<1><<<256, 512, 0, stream>>>(BuH, C2, 1024, 512, 1, 16, nullptr, y_out, D_vec, xb);
}